// Round 6
// baseline (721.204 us; speedup 1.0000x reference)
//
#include <hip/hip_runtime.h>

#define VOCAB 50000
#define OOV   100
#define EXT   50100
#define UNITS 512
#define EMB   256
#define NS    32
#define NW    50
#define BATCH 64
#define NQ    8
#define BINS_PER ((EXT + NQ - 1) / NQ)   // 6263

#define GKC   24  // gru k-split chunks of 32
#define QKC   8   // q/qw k-split chunks of 64
#define HKC   16  // ht k-split chunks of 64
#define NCB   ((VOCAB + 63) / 64)        // 782 column tiles of 64
#define WORDB (BATCH * NS)               // 2048 word blocks in k_fw

#define COPYB (NQ * BATCH)               // 512 blocks for copy part of k_tail
#define FINB  ((BATCH * (EXT / 4) + 255) / 256)  // 3132 blocks for final part

using short8 = __attribute__((ext_vector_type(8))) short;
using f32x4  = __attribute__((ext_vector_type(4))) float;

__device__ __forceinline__ float sigmoidf_(float x) { return 1.f / (1.f + __expf(-x)); }

// fp32 -> bf16 round-to-nearest (ties up; within 1 ulp of RNE)
__device__ __forceinline__ unsigned short f2bf_(float x) {
  union { float f; unsigned u; } c; c.f = x;
  return (unsigned short)((c.u + 0x8000u) >> 16);
}

// async global->LDS, 16B per lane; LDS dest = wave-uniform base + lane*16
__device__ __forceinline__ void gload_lds16(const void* g, void* l) {
  __builtin_amdgcn_global_load_lds(
      (const __attribute__((address_space(1))) unsigned int*)g,
      (__attribute__((address_space(3))) unsigned int*)l, 16, 0, 0);
}

// ---- K1: GRU partial + last-block gate finalize. grid (GKC, BATCH), 256 thr ----
__global__ __launch_bounds__(256) void k_gru(
    const float* __restrict__ emb, const float* __restrict__ h0,
    const float* __restrict__ Wx, const float* __restrict__ Wh,
    const float* __restrict__ gb, const float* __restrict__ whid,
    const float* __restrict__ winp,
    float* __restrict__ gates, float* __restrict__ ws_dec,
    float* __restrict__ out_dec, float* __restrict__ ws_pgen,
    unsigned* __restrict__ cnt)
{
  __shared__ float sv[32];
  __shared__ float sred[256];
  __shared__ unsigned sticket;
  const int kc = blockIdx.x, b = blockIdx.y, t = threadIdx.x, u0 = 2 * t;
  const int base = kc * 32;
  const bool isx = base < EMB;
  if (t < 32) sv[t] = isx ? emb[b * EMB + base + t] : h0[b * UNITS + base - EMB + t];
  __syncthreads();

  const float* W = isx ? (Wx + (size_t)base * 1536) : (Wh + (size_t)(base - EMB) * 1536);
  float azx = 0.f, azy = 0.f, arx = 0.f, ary = 0.f, ahxx = 0.f, ahy = 0.f;
  for (int i = 0; i < 32; i += 4) {
    float2 wz[4], wr[4], wh[4];
#pragma unroll
    for (int j = 0; j < 4; ++j) {
      const float* row = W + (size_t)(i + j) * 1536;
      wz[j] = *(const float2*)(row + u0);
      wr[j] = *(const float2*)(row + 512 + u0);
      wh[j] = *(const float2*)(row + 1024 + u0);
    }
#pragma unroll
    for (int j = 0; j < 4; ++j) {
      const float v = sv[i + j];
      azx = fmaf(v, wz[j].x, azx); azy = fmaf(v, wz[j].y, azy);
      arx = fmaf(v, wr[j].x, arx); ary = fmaf(v, wr[j].y, ary);
      ahxx = fmaf(v, wh[j].x, ahxx); ahy = fmaf(v, wh[j].y, ahy);
    }
  }
  float* gb_ = gates + (size_t)b * 2048;
  atomicAdd(gb_ + u0, azx);           atomicAdd(gb_ + u0 + 1, azy);
  atomicAdd(gb_ + 512 + u0, arx);     atomicAdd(gb_ + 512 + u0 + 1, ary);
  const int ho = isx ? 1024 : 1536;
  atomicAdd(gb_ + ho + u0, ahxx);     atomicAdd(gb_ + ho + u0 + 1, ahy);

  // ---- ticket: last block for this b finalizes ----
  __threadfence();
  __syncthreads();
  if (t == 0) sticket = atomicAdd(&cnt[b], 1u);
  __syncthreads();
  if (sticket != GKC - 1) return;
  __threadfence();   // acquire: see all blocks' atomics

  const float* g_ = gates + (size_t)b * 2048;
  const float2 az  = *(const float2*)(g_ + u0);
  const float2 ar  = *(const float2*)(g_ + 512 + u0);
  const float2 ahx = *(const float2*)(g_ + 1024 + u0);
  const float2 ahh = *(const float2*)(g_ + 1536 + u0);

  const float2 b0z = *(const float2*)(gb + u0);
  const float2 b0r = *(const float2*)(gb + 512 + u0);
  const float2 b0h = *(const float2*)(gb + 1024 + u0);
  const float2 b1z = *(const float2*)(gb + 1536 + u0);
  const float2 b1r = *(const float2*)(gb + 1536 + 512 + u0);
  const float2 b1h = *(const float2*)(gb + 1536 + 1024 + u0);
  const float2 hp  = *(const float2*)(h0 + b * UNITS + u0);

  const float z0 = sigmoidf_(az.x + b0z.x + b1z.x);
  const float z1 = sigmoidf_(az.y + b0z.y + b1z.y);
  const float r0 = sigmoidf_(ar.x + b0r.x + b1r.x);
  const float r1 = sigmoidf_(ar.y + b0r.y + b1r.y);
  const float c0 = tanhf(ahx.x + b0h.x + r0 * (ahh.x + b1h.x));
  const float c1 = tanhf(ahx.y + b0h.y + r1 * (ahh.y + b1h.y));
  const float n0 = z0 * hp.x + (1.f - z0) * c0;
  const float n1 = z1 * hp.y + (1.f - z1) * c1;
  ws_dec[b * UNITS + u0]      = n0;
  ws_dec[b * UNITS + u0 + 1]  = n1;
  out_dec[b * UNITS + u0]     = n0;
  out_dec[b * UNITS + u0 + 1] = n1;

  float p = n0 * whid[u0] + n1 * whid[u0 + 1];
  if (u0 < EMB) p += emb[b * EMB + u0] * winp[u0] + emb[b * EMB + u0 + 1] * winp[u0 + 1];
  sred[t] = p;
  __syncthreads();
  for (int off = 128; off > 0; off >>= 1) {
    if (t < off) sred[t] += sred[t + off];
    __syncthreads();
  }
  if (t == 0) atomicAdd(ws_pgen + b, sred[0]);
}

// ---- K2: q/qw partial + last-block attention finalize. grid (QKC, BATCH), 256 thr ----
__global__ __launch_bounds__(256) void k_qa(
    const float* __restrict__ ws_dec, const float* __restrict__ Wsent,
    const float* __restrict__ Wword, const float* __restrict__ encS,
    const float* __restrict__ wctx,
    float* __restrict__ qsum, float* __restrict__ ws_alpha,
    float* __restrict__ ctxsum, float* __restrict__ ws_pgen,
    unsigned* __restrict__ cnt)
{
  __shared__ float sdec[64];
  __shared__ float sq[UNITS];
  __shared__ float sscore[NS], salpha[NS];
  __shared__ float sred[256];
  __shared__ unsigned sticket;
  const int kc = blockIdx.x, b = blockIdx.y, t = threadIdx.x, u0 = 2 * t;
  const int k0 = kc * 64;
  if (t < 64) sdec[t] = ws_dec[b * UNITS + k0 + t];
  __syncthreads();

  float qx = 0.f, qy = 0.f, wx = 0.f, wy = 0.f;
  for (int i = 0; i < 64; i += 4) {
    float2 a[4], c[4];
#pragma unroll
    for (int j = 0; j < 4; ++j) {
      a[j] = *(const float2*)(Wsent + (size_t)(k0 + i + j) * UNITS + u0);
      c[j] = *(const float2*)(Wword + (size_t)(k0 + i + j) * UNITS + u0);
    }
#pragma unroll
    for (int j = 0; j < 4; ++j) {
      const float d = sdec[i + j];
      qx = fmaf(d, a[j].x, qx); qy = fmaf(d, a[j].y, qy);
      wx = fmaf(d, c[j].x, wx); wy = fmaf(d, c[j].y, wy);
    }
  }
  float* o = qsum + (size_t)b * 1024;
  atomicAdd(o + u0, qx);           atomicAdd(o + u0 + 1, qy);
  atomicAdd(o + 512 + u0, wx);     atomicAdd(o + 512 + u0 + 1, wy);

  // ---- ticket ----
  __threadfence();
  __syncthreads();
  if (t == 0) sticket = atomicAdd(&cnt[b], 1u);
  __syncthreads();
  if (sticket != QKC - 1) return;
  __threadfence();

  sq[t]       = o[t];
  sq[t + 256] = o[t + 256];
  __syncthreads();

  const int wave = t >> 6, lane = t & 63;
  float qr[8];
#pragma unroll
  for (int j = 0; j < 8; ++j) qr[j] = sq[lane * 8 + j];
  for (int s = wave; s < NS; s += 4) {
    const float* base = encS + ((size_t)(b * NS + s)) * UNITS + lane * 8;
    const float4 v0 = *(const float4*)(base);
    const float4 v1 = *(const float4*)(base + 4);
    float acc = 0.f;
    acc = fmaf(v0.x, qr[0], acc); acc = fmaf(v0.y, qr[1], acc);
    acc = fmaf(v0.z, qr[2], acc); acc = fmaf(v0.w, qr[3], acc);
    acc = fmaf(v1.x, qr[4], acc); acc = fmaf(v1.y, qr[5], acc);
    acc = fmaf(v1.z, qr[6], acc); acc = fmaf(v1.w, qr[7], acc);
#pragma unroll
    for (int off = 32; off > 0; off >>= 1) acc += __shfl_down(acc, off);
    if (lane == 0) sscore[s] = acc;
  }
  __syncthreads();

  if (t < 32) {
    const float v = sscore[t];
    float m = v;
#pragma unroll
    for (int off = 16; off > 0; off >>= 1) m = fmaxf(m, __shfl_xor(m, off));
    const float e = __expf(v - m);
    float ssum = e;
#pragma unroll
    for (int off = 16; off > 0; off >>= 1) ssum += __shfl_xor(ssum, off);
    const float a = e / ssum;
    salpha[t] = a;
    ws_alpha[b * NS + t] = a;
  }
  __syncthreads();

  float c0 = 0.f, c1 = 0.f;
#pragma unroll 4
  for (int s = 0; s < NS; ++s) {
    const float* es = encS + ((size_t)(b * NS + s)) * UNITS;
    c0 = fmaf(salpha[s], es[t], c0);
    c1 = fmaf(salpha[s], es[t + 256], c1);
  }
  ctxsum[b * UNITS + t]       = c0;
  ctxsum[b * UNITS + t + 256] = c1;

  sred[t] = c0 * wctx[t] + c1 * wctx[t + 256];
  __syncthreads();
  for (int off = 128; off > 0; off >>= 1) {
    if (t < off) sred[t] += sred[t + off];
    __syncthreads();
  }
  if (t == 0) atomicAdd(ws_pgen + b, sred[0]);
}

// ---- K3: hidden_t partial + last-block tanh/A-frag/p_gen finalize. grid (HKC, BATCH), 128 thr ----
__global__ __launch_bounds__(128) void k_hta(
    const float* __restrict__ ctxsum, const float* __restrict__ ws_dec,
    const float* __restrict__ wdec, const float* __restrict__ ws_pgen,
    float* __restrict__ htsum, unsigned short* __restrict__ Af,
    float* __restrict__ out_pgen, unsigned* __restrict__ cnt)
{
  __shared__ float scat[64];
  __shared__ unsigned sticket;
  const int kc = blockIdx.x, b = blockIdx.y, t = threadIdx.x, u0 = 2 * t;
  const int k0 = kc * 64;
  if (t < 64) {
    const int k = k0 + t;
    scat[t] = (k < UNITS) ? ctxsum[b * UNITS + k] : ws_dec[b * UNITS + k - UNITS];
  }
  __syncthreads();

  float ax = 0.f, ay = 0.f;
  for (int i = 0; i < 64; i += 8) {
    float2 w[8];
#pragma unroll
    for (int j = 0; j < 8; ++j)
      w[j] = *(const float2*)(wdec + (size_t)(k0 + i + j) * 256 + u0);
#pragma unroll
    for (int j = 0; j < 8; ++j) {
      const float v = scat[i + j];
      ax = fmaf(v, w[j].x, ax); ay = fmaf(v, w[j].y, ay);
    }
  }
  atomicAdd(htsum + b * EMB + u0, ax);
  atomicAdd(htsum + b * EMB + u0 + 1, ay);

  // ---- global ticket: very last block finalizes everything ----
  __threadfence();
  __syncthreads();
  if (t == 0) sticket = atomicAdd(cnt, 1u);
  __syncthreads();
  if (sticket != HKC * BATCH - 1) return;
  __threadfence();

  const int l = t & 63, wv = t >> 6;
#pragma unroll
  for (int rb = 0; rb < 4; ++rb) {
    for (int ks = wv; ks < 8; ks += 2) {
      const int row = rb * 16 + (l & 15);
      const int kk = ks * 32 + (l >> 4) * 8;
      const float4 h0v = *(const float4*)(htsum + row * EMB + kk);
      const float4 h1v = *(const float4*)(htsum + row * EMB + kk + 4);
      short8 v;
      v[0] = (short)f2bf_(tanhf(h0v.x)); v[1] = (short)f2bf_(tanhf(h0v.y));
      v[2] = (short)f2bf_(tanhf(h0v.z)); v[3] = (short)f2bf_(tanhf(h0v.w));
      v[4] = (short)f2bf_(tanhf(h1v.x)); v[5] = (short)f2bf_(tanhf(h1v.y));
      v[6] = (short)f2bf_(tanhf(h1v.z)); v[7] = (short)f2bf_(tanhf(h1v.w));
      *(short8*)(Af + ((size_t)(rb * 8 + ks)) * 512 + l * 8) = v;
    }
  }
  if (t < BATCH) out_pgen[t] = sigmoidf_(ws_pgen[t]);
}

// ---- K_fw: horizontal fusion of word-attention and MFMA FC ----
// blocks [0, WORDB): word attention -> beta (block per (b,s))
// blocks [WORDB, WORDB+NCB): FC column tile (32KB two-phase LDS stage)
__global__ __launch_bounds__(256, 5) void k_fw(
    const unsigned short* __restrict__ Af, const float* __restrict__ fcW,
    const float* __restrict__ fcb, const float* __restrict__ qsum,
    const float* __restrict__ encW, const float* __restrict__ ws_alpha,
    float* __restrict__ out_gen, float* __restrict__ ws_rowsum,
    float* __restrict__ ws_beta)
{
  __shared__ __align__(16) float smem[8192];   // 32 KB, shared by both branches
  const int bid = blockIdx.x, t = threadIdx.x;

  if (bid < WORDB) {
    // ---------------- word body ----------------
    float* sqw    = smem;          // 512
    float* sscore = smem + 512;    // 64
    const int b = bid >> 5, s = bid & 31;
    sqw[t]       = qsum[(size_t)b * 1024 + 512 + t];
    sqw[t + 256] = qsum[(size_t)b * 1024 + 768 + t];
    __syncthreads();

    const int wave = t >> 6, lane = t & 63;
    float qr[8];
#pragma unroll
    for (int j = 0; j < 8; ++j) qr[j] = sqw[lane * 8 + j];
    const float* base = encW + ((size_t)(b * NS + s)) * NW * UNITS + lane * 8;

#pragma unroll
    for (int i = 0; i < 4; ++i) {
      const int r0 = i * 16 + wave * 4;     // wave-uniform
      if (r0 >= NW) break;
      float a0 = 0.f, a1 = 0.f, a2 = 0.f, a3 = 0.f;
      {
        const float* row = base + (size_t)r0 * UNITS;
        const float4 v0 = *(const float4*)(row);
        const float4 v1 = *(const float4*)(row + 4);
        a0 = v0.x*qr[0] + v0.y*qr[1] + v0.z*qr[2] + v0.w*qr[3]
           + v1.x*qr[4] + v1.y*qr[5] + v1.z*qr[6] + v1.w*qr[7];
      }
      if (r0 + 1 < NW) {
        const float* row = base + (size_t)(r0 + 1) * UNITS;
        const float4 v0 = *(const float4*)(row);
        const float4 v1 = *(const float4*)(row + 4);
        a1 = v0.x*qr[0] + v0.y*qr[1] + v0.z*qr[2] + v0.w*qr[3]
           + v1.x*qr[4] + v1.y*qr[5] + v1.z*qr[6] + v1.w*qr[7];
      }
      if (r0 + 2 < NW) {
        const float* row = base + (size_t)(r0 + 2) * UNITS;
        const float4 v0 = *(const float4*)(row);
        const float4 v1 = *(const float4*)(row + 4);
        a2 = v0.x*qr[0] + v0.y*qr[1] + v0.z*qr[2] + v0.w*qr[3]
           + v1.x*qr[4] + v1.y*qr[5] + v1.z*qr[6] + v1.w*qr[7];
      }
      if (r0 + 3 < NW) {
        const float* row = base + (size_t)(r0 + 3) * UNITS;
        const float4 v0 = *(const float4*)(row);
        const float4 v1 = *(const float4*)(row + 4);
        a3 = v0.x*qr[0] + v0.y*qr[1] + v0.z*qr[2] + v0.w*qr[3]
           + v1.x*qr[4] + v1.y*qr[5] + v1.z*qr[6] + v1.w*qr[7];
      }
#pragma unroll
      for (int off = 32; off > 0; off >>= 1) {
        a0 += __shfl_xor(a0, off);
        a1 += __shfl_xor(a1, off);
        a2 += __shfl_xor(a2, off);
        a3 += __shfl_xor(a3, off);
      }
      if (lane == 0) {
        sscore[r0] = a0;
        if (r0 + 1 < NW) sscore[r0 + 1] = a1;
        if (r0 + 2 < NW) sscore[r0 + 2] = a2;
        if (r0 + 3 < NW) sscore[r0 + 3] = a3;
      }
    }
    __syncthreads();

    if (t < 64) {
      const float v = (t < NW) ? sscore[t] : -1e30f;
      float m = v;
#pragma unroll
      for (int off = 32; off > 0; off >>= 1) m = fmaxf(m, __shfl_xor(m, off));
      const float e = (t < NW) ? __expf(v - m) : 0.f;
      float sum = e;
#pragma unroll
      for (int off = 32; off > 0; off >>= 1) sum += __shfl_xor(sum, off);
      if (t < NW)
        ws_beta[b * (NS * NW) + s * NW + t] = ws_alpha[b * NS + s] * e / sum;
    }
    return;
  }

  // ---------------- fc body ----------------
  const int cb = bid - WORDB;
  float* swt = smem;               // [128 k][64 c] fp32, 32 KB per phase
  const int rb = t >> 6, l = t & 63;

  short8 a[8];
#pragma unroll
  for (int ks = 0; ks < 8; ++ks)
    a[ks] = *(const short8*)(Af + ((size_t)(rb * 8 + ks)) * 512 + l * 8);

  f32x4 acc0 = {0.f, 0.f, 0.f, 0.f};
  f32x4 acc1 = {0.f, 0.f, 0.f, 0.f};
  f32x4 acc2 = {0.f, 0.f, 0.f, 0.f};
  f32x4 acc3 = {0.f, 0.f, 0.f, 0.f};

  const int cr = l & 15;          // col within 16-group
  const int kb = (l >> 4) * 8;    // k sub-base within 32
  const int gc = cb * 64 + cr * 4;
  const bool oob = (gc >= VOCAB);           // VOCAB%4==0 -> groups fully in/out

#pragma unroll
  for (int h = 0; h < 2; ++h) {
    if (h) __syncthreads();       // all waves done reading phase-0 tile
    // stage k rows [h*128, h*128+128): wave rb covers rb*32..rb*32+31
    const int krow0 = h * 128 + rb * 32;
#pragma unroll
    for (int q = 0; q < 8; ++q) {
      const float* src = oob ? (fcW + cr * 4)
          : (fcW + (size_t)(krow0 + q * 4 + (l >> 4)) * VOCAB + gc);
      gload_lds16(src, swt + (rb * 32 + q * 4) * 64);
    }
    __syncthreads();              // vmcnt(0) drain: tile ready

#pragma unroll
    for (int ks2 = 0; ks2 < 4; ++ks2) {
      const float* kbase = swt + (size_t)(ks2 * 32 + kb) * 64 + cr;
      short8 b0, b1, b2, b3;
#pragma unroll
      for (int j = 0; j < 8; ++j) {
        const float* rowp = kbase + j * 64;
        b0[j] = (short)f2bf_(rowp[0]);
        b1[j] = (short)f2bf_(rowp[16]);
        b2[j] = (short)f2bf_(rowp[32]);
        b3[j] = (short)f2bf_(rowp[48]);
      }
      const int ks = h * 4 + ks2;
      acc0 = __builtin_amdgcn_mfma_f32_16x16x32_bf16(a[ks], b0, acc0, 0, 0, 0);
      acc1 = __builtin_amdgcn_mfma_f32_16x16x32_bf16(a[ks], b1, acc1, 0, 0, 0);
      acc2 = __builtin_amdgcn_mfma_f32_16x16x32_bf16(a[ks], b2, acc2, 0, 0, 0);
      acc3 = __builtin_amdgcn_mfma_f32_16x16x32_bf16(a[ks], b3, acc3, 0, 0, 0);
    }
  }

  // D layout: col = l&15 (+f*16), row = (l>>4)*4 + p  [m89-verified]
  const int colbase = cb * 64 + (l & 15);
  const int rowbase = rb * 16 + (l >> 4) * 4;
#pragma unroll
  for (int p = 0; p < 4; ++p) {
    float rs = 0.f;
    const float av[4] = {acc0[p], acc1[p], acc2[p], acc3[p]};
#pragma unroll
    for (int f = 0; f < 4; ++f) {
      const int col = colbase + f * 16;
      if (col < VOCAB) {
        const float e = __expf(av[f] + fcb[col]);   // logits tiny; no max-shift
        out_gen[(size_t)(rowbase + p) * EXT + col] = e;
        rs += e;
      }
    }
    rs += __shfl_xor(rs, 1); rs += __shfl_xor(rs, 2);
    rs += __shfl_xor(rs, 4); rs += __shfl_xor(rs, 8);
    if ((l & 15) == 0) atomicAdd(ws_rowsum + rowbase + p, rs);
  }
}

// ---- K_tail: horizontal fusion of copy-histogram and gen-normalize ----
__global__ __launch_bounds__(256) void k_tail(
    const int* __restrict__ nidx, const float* __restrict__ ws_beta,
    const float* __restrict__ ws_rowsum, float* __restrict__ out_copy,
    float* __restrict__ out_gen)
{
  __shared__ float shist[BINS_PER];
  const int bid = blockIdx.x, t = threadIdx.x;
  if (bid < COPYB) {
    const int q = bid & (NQ - 1), b = bid >> 3;
    const int base = q * BINS_PER;
    const int len = min(BINS_PER, EXT - base);

    for (int j = t; j < BINS_PER; j += 256) shist[j] = 0.f;
    __syncthreads();

    for (int e = t; e < NS * NW; e += 256) {
      const int rel = nidx[b * (NS * NW) + e] - base;
      if (rel >= 0 && rel < len) atomicAdd(shist + rel, ws_beta[b * (NS * NW) + e]);
    }
    __syncthreads();

    for (int j = t; j < len; j += 256)
      out_copy[(size_t)b * EXT + base + j] = shist[j];
  } else {
    const int i4 = (bid - COPYB) * 256 + t;
    if (i4 < BATCH * (EXT / 4)) {
      const int b = i4 / (EXT / 4);
      const int c4 = (i4 - b * (EXT / 4)) * 4;
      float4 v = make_float4(0.f, 0.f, 0.f, 0.f);
      if (c4 < VOCAB) {
        v = *(const float4*)(out_gen + (size_t)b * EXT + c4);
        const float inv = 1.f / ws_rowsum[b];
        v.x *= inv; v.y *= inv; v.z *= inv; v.w *= inv;
      }
      *(float4*)(out_gen + (size_t)b * EXT + c4) = v;
    }
  }
}

extern "C" void kernel_launch(void* const* d_in, const int* in_sizes, int n_in,
                              void* d_out, int out_size, void* d_ws, size_t ws_size,
                              hipStream_t stream)
{
  const float* emb   = (const float*)d_in[0];
  const float* h0    = (const float*)d_in[1];
  const float* encS  = (const float*)d_in[2];
  const float* encW  = (const float*)d_in[3];
  const int*   nidx  = (const int*)d_in[4];
  const float* Wx    = (const float*)d_in[6];
  const float* Wh    = (const float*)d_in[7];
  const float* gb    = (const float*)d_in[8];
  const float* Wsent = (const float*)d_in[9];
  const float* Wword = (const float*)d_in[10];
  const float* fcW   = (const float*)d_in[11];
  const float* fcb   = (const float*)d_in[12];
  const float* wctx  = (const float*)d_in[13];
  const float* whid  = (const float*)d_in[14];
  const float* wdec  = (const float*)d_in[15];
  const float* winp  = (const float*)d_in[16];

  float* ws = (float*)d_ws;
  // zeroed region (single memset): gates | qsum | ctxsum | htsum | rowsum | pgen | counters
  float* ws_gates  = ws;                          // 64*2048
  float* ws_qsum   = ws_gates + BATCH * 2048;     // 64*1024
  float* ws_ctxsum = ws_qsum + BATCH * 1024;      // 64*512
  float* ws_htsum  = ws_ctxsum + BATCH * UNITS;   // 64*256
  float* ws_rowsum = ws_htsum + BATCH * EMB;      // 64
  float* ws_pgen   = ws_rowsum + BATCH;           // 64
  unsigned* ws_cnt = (unsigned*)(ws_pgen + BATCH);// 192 (gru 64 | qa 64 | ht 1)
  const size_t zfloats = (size_t)BATCH * (2048 + 1024 + 512 + 256) + 2 * BATCH + 192;
  // non-zeroed:
  float* ws_dec    = (float*)(ws_cnt + 192);      // 64*512
  float* ws_alpha  = ws_dec + BATCH * UNITS;      // 64*32
  float* ws_beta   = ws_alpha + BATCH * NS;       // 64*1600
  unsigned short* ws_af = (unsigned short*)(ws_beta + BATCH * NS * NW);  // 16384 bf16

  float* out      = (float*)d_out;
  float* out_dec  = out;                                   // 64*512
  float* out_gen  = out + BATCH * UNITS;                   // 64*50100
  float* out_copy = out_gen + (size_t)BATCH * EXT;         // 64*50100
  float* out_pgen = out_copy + (size_t)BATCH * EXT;        // 64

  hipMemsetAsync(ws, 0, zfloats * sizeof(float), stream);

  k_gru<<<dim3(GKC, BATCH), 256, 0, stream>>>(emb, h0, Wx, Wh, gb, whid, winp,
                                              ws_gates, ws_dec, out_dec,
                                              ws_pgen, ws_cnt);
  k_qa<<<dim3(QKC, BATCH), 256, 0, stream>>>(ws_dec, Wsent, Wword, encS, wctx,
                                             ws_qsum, ws_alpha, ws_ctxsum,
                                             ws_pgen, ws_cnt + 64);
  k_hta<<<dim3(HKC, BATCH), 128, 0, stream>>>(ws_ctxsum, ws_dec, wdec, ws_pgen,
                                              ws_htsum, ws_af, out_pgen,
                                              ws_cnt + 128);
  k_fw<<<WORDB + NCB, 256, 0, stream>>>(ws_af, fcW, fcb, ws_qsum, encW,
                                        ws_alpha, out_gen, ws_rowsum, ws_beta);
  k_tail<<<COPYB + FINB, 256, 0, stream>>>(nidx, ws_beta, ws_rowsum,
                                           out_copy, out_gen);
}